// Round 2
// baseline (419.455 us; speedup 1.0000x reference)
//
#include <hip/hip_runtime.h>
#include <hip/hip_bf16.h>

// Problem constants
#define BB 64     // batch
#define NT 128    // text tokens
#define NV 256    // visual tokens
#define DD 512    // feature dim (bytes per row in fp8)
#define BKB 128   // K-chunk in bytes: one 16x16x128 f8f6f4 k-step
#define BM 256    // M-tile rows (= 2 text batches)
#define BN 256    // N-tile rows (= 1 visual batch)
#define EPSF 1e-7f

typedef __attribute__((ext_vector_type(8))) int i32x8;
typedef __attribute__((ext_vector_type(4))) int i32x4;
typedef __attribute__((ext_vector_type(4))) float f32x4;

__device__ __forceinline__ void glds16(const uchar* g, uchar* l) {
    __builtin_amdgcn_global_load_lds(
        (const __attribute__((address_space(1))) unsigned int*)g,
        (__attribute__((address_space(3))) unsigned int*)l, 16, 0, 0);
}

// ---------------------------------------------------------------------------
// Kernel 1: L2-normalize rows, write fp8 e4m3 (OCP). Wave per row.
// ---------------------------------------------------------------------------
__global__ __launch_bounds__(256) void k_normalize(
    const float* __restrict__ tf, const float* __restrict__ vf,
    uchar* __restrict__ tn, uchar* __restrict__ vn,
    float* __restrict__ reg_sum) {
    if (blockIdx.x == 0 && threadIdx.x == 0) *reg_sum = 0.0f;
    const int w = threadIdx.x >> 6, l = threadIdx.x & 63;
    const int row = blockIdx.x * 4 + w;
    const float* src;
    uchar* dst;
    if (row < BB * NT) {
        src = tf + (size_t)row * DD;
        dst = tn + (size_t)row * DD;
    } else {
        int r = row - BB * NT;
        src = vf + (size_t)r * DD;
        dst = vn + (size_t)r * DD;
    }
    float4 x0 = ((const float4*)src)[l * 2];
    float4 x1 = ((const float4*)src)[l * 2 + 1];
    float ss = x0.x * x0.x + x0.y * x0.y + x0.z * x0.z + x0.w * x0.w
             + x1.x * x1.x + x1.y * x1.y + x1.z * x1.z + x1.w * x1.w;
    #pragma unroll
    for (int off = 32; off; off >>= 1) ss += __shfl_xor(ss, off, 64);
    float scale = 1.0f / fmaxf(sqrtf(ss), 1e-12f);
    int p0 = __builtin_amdgcn_cvt_pk_fp8_f32(x0.x * scale, x0.y * scale, 0, 0);
    p0 = __builtin_amdgcn_cvt_pk_fp8_f32(x0.z * scale, x0.w * scale, p0, 1);
    int p1 = __builtin_amdgcn_cvt_pk_fp8_f32(x1.x * scale, x1.y * scale, 0, 0);
    p1 = __builtin_amdgcn_cvt_pk_fp8_f32(x1.z * scale, x1.w * scale, p1, 1);
    ((uint2*)dst)[l] = make_uint2((unsigned)p0, (unsigned)p1);
}

// ---------------------------------------------------------------------------
// Kernel 2: 256x256-tile MX-fp8 GEMM, double-buffered LDS, prefetch-then-
// compute with ONE plain __syncthreads() per K-step (T3-minimum 2-phase:
// stage(next) issued BEFORE compute(cur); the barrier's implicit vmcnt(0)
// drain lands after ~2.2k cycles of MFMA so the prefetch is already home).
// No inline asm anywhere.
// Tile spans text rows of batches (2bx, 2bx+1) x all 256 visual rows of
// batch by -> complete row-max + masked mean per block, two clip_sims out.
// 8 waves arranged 2x4 -> wave tile 128x64: acc 8x4 f32x4 = 128 VGPRs.
// LDS rotation swizzle p=(g+row)&7 on the DMA global-address side (dest
// lane-contiguous as global_load_lds requires), mirrored on frag reads
// -> uniform 8 lanes/granule on ds_read_b128, conflict-free (verified in
// the 247us baseline, absmax 0.0).
// ---------------------------------------------------------------------------
__global__ __launch_bounds__(512, 2) void k_gemm(
    const uchar* __restrict__ tn, const uchar* __restrict__ vn,
    const int* __restrict__ mask,
    float* __restrict__ clip_sims, float* __restrict__ reg_sum) {
    __shared__ uchar sT[2][BM * BKB];   // 2 x 32 KB
    __shared__ uchar sV[2][BN * BKB];   // 2 x 32 KB
    __shared__ float maxbuf[BM][4];     // row-max partials per wave col-group
    __shared__ float redw[8];
    __shared__ float c0[4], c1[4];

    // XCD-aware bijective swizzle: 2048 blocks, 8 XCDs, 256 each.
    const int bid = blockIdx.x;
    const int swz = (bid & 7) * 256 + (bid >> 3);
    const int bx = swz & 31;   // text-pair tile (0..31)
    const int by = swz >> 5;   // visual batch j (0..63)

    const int tid = threadIdx.x;
    const int l = tid & 63, w = tid >> 6;
    const int wr = w >> 2, wc = w & 3;      // wave row-group (0..1), col-group (0..3)
    const int m15 = l & 15, q = l >> 4;

    const uchar* tbase = tn + (size_t)bx * BM * DD;
    const uchar* vbase = vn + (size_t)by * NV * DD;

    // Staging: 16B unit f -> row r = f>>3, phys granule p = f&7 holds
    // logical granule g = (p - r) & 7. Same geometry for T and V (256x128B).
    int soff[4];
    #pragma unroll
    for (int s = 0; s < 4; ++s) {
        int f = s * 512 + tid;
        int r = f >> 3, p = f & 7, g = (p - r) & 7;
        soff[s] = r * DD + g * 16;
    }

    // Fragment read addresses: lane holds k = q*32..q*32+31 of its row,
    // logical granules 2q, 2q+1 -> phys (2q+row)&7, (2q+1+row)&7.
    int a_b0[8], a_b1[8], b_b0[4], b_b1[4];
    #pragma unroll
    for (int rt = 0; rt < 8; ++rt) {
        int row = wr * 128 + rt * 16 + m15;
        a_b0[rt] = row * BKB + (((2 * q + row) & 7) * 16);
        a_b1[rt] = row * BKB + (((2 * q + 1 + row) & 7) * 16);
    }
    #pragma unroll
    for (int ct = 0; ct < 4; ++ct) {
        int row = wc * 64 + ct * 16 + m15;
        b_b0[ct] = row * BKB + (((2 * q + row) & 7) * 16);
        b_b1[ct] = row * BKB + (((2 * q + 1 + row) & 7) * 16);
    }

    f32x4 acc[8][4];
    #pragma unroll
    for (int rt = 0; rt < 8; ++rt)
        #pragma unroll
        for (int ct = 0; ct < 4; ++ct) acc[rt][ct] = (f32x4){0.f, 0.f, 0.f, 0.f};

    // Prologue: stage chunk 0 into buffer 0, then one full sync.
    #pragma unroll
    for (int s = 0; s < 4; ++s) {
        glds16(tbase + soff[s], sT[0] + (s * 512 + tid) * 16);
        glds16(vbase + soff[s], sV[0] + (s * 512 + tid) * 16);
    }
    __syncthreads();

    #pragma unroll
    for (int ks = 0; ks < 4; ++ks) {
        const int cur = ks & 1, nxt = cur ^ 1;
        // Issue next chunk's staging FIRST (overlaps with compute below).
        // Overwrite of buf[nxt] is safe: the barrier at the end of the
        // previous iteration guarantees all waves finished reading it.
        if (ks < 3) {
            const int kk = (ks + 1) * BKB;
            #pragma unroll
            for (int s = 0; s < 4; ++s) {
                glds16(tbase + soff[s] + kk, sT[nxt] + (s * 512 + tid) * 16);
                glds16(vbase + soff[s] + kk, sV[nxt] + (s * 512 + tid) * 16);
            }
        }

        // Compute current chunk.
        i32x8 b[4];
        #pragma unroll
        for (int ct = 0; ct < 4; ++ct) {
            i32x4 lo = *(const i32x4*)(sV[cur] + b_b0[ct]);
            i32x4 hi = *(const i32x4*)(sV[cur] + b_b1[ct]);
            b[ct] = (i32x8){lo.x, lo.y, lo.z, lo.w, hi.x, hi.y, hi.z, hi.w};
        }
        #pragma unroll
        for (int rt = 0; rt < 8; ++rt) {
            i32x4 lo = *(const i32x4*)(sT[cur] + a_b0[rt]);
            i32x4 hi = *(const i32x4*)(sT[cur] + a_b1[rt]);
            i32x8 a = (i32x8){lo.x, lo.y, lo.z, lo.w, hi.x, hi.y, hi.z, hi.w};
            #pragma unroll
            for (int ct = 0; ct < 4; ++ct)
                acc[rt][ct] = __builtin_amdgcn_mfma_scale_f32_16x16x128_f8f6f4(
                    a, b[ct], acc[rt][ct],
                    0 /*A fmt=fp8*/, 0 /*B fmt=fp8*/,
                    0, 127 /*scaleA=1.0*/, 0, 127 /*scaleB=1.0*/);
        }

        // One barrier per K-step: drains the prefetch (already landed under
        // the MFMAs) and fences the buffer swap.
        __syncthreads();
    }

    // Epilogue 1: reg partial = sum of min(s,0)^2 over this lane's 128 values.
    float rp = 0.0f;
    #pragma unroll
    for (int rt = 0; rt < 8; ++rt)
        #pragma unroll
        for (int ct = 0; ct < 4; ++ct)
            #pragma unroll
            for (int r = 0; r < 4; ++r) {
                float m = fminf(acc[rt][ct][r], 0.0f);
                rp = fmaf(m, m, rp);
            }

    // Epilogue 2: row max. C/D layout: col = lane&15, row = q*4 + reg.
    #pragma unroll
    for (int rt = 0; rt < 8; ++rt)
        #pragma unroll
        for (int r = 0; r < 4; ++r) {
            float m = acc[rt][0][r];
            #pragma unroll
            for (int ct = 1; ct < 4; ++ct) m = fmaxf(m, acc[rt][ct][r]);
            #pragma unroll
            for (int msk = 1; msk < 16; msk <<= 1)
                m = fmaxf(m, __shfl_xor(m, msk, 64));
            if (m15 == 0)
                maxbuf[wr * 128 + rt * 16 + q * 4 + r][wc] = m;
        }

    #pragma unroll
    for (int off = 32; off; off >>= 1) rp += __shfl_down(rp, off, 64);
    if (l == 0) redw[w] = rp;
    __syncthreads();

    // Fused clip: masked mean of row maxes per 128-token group.
    // Waves 0-1 -> batch 2bx (rows 0..127), waves 2-3 -> batch 2bx+1.
    if (tid < 256) {
        float rm = fmaxf(fmaxf(maxbuf[tid][0], maxbuf[tid][1]),
                         fmaxf(maxbuf[tid][2], maxbuf[tid][3]));
        int ib = bx * 2 + (tid >> 7);
        float mf = (float)mask[ib * NT + (tid & 127)];
        float v = rm * mf;
        #pragma unroll
        for (int off = 32; off; off >>= 1) {
            v += __shfl_down(v, off, 64);
            mf += __shfl_down(mf, off, 64);
        }
        if (l == 0) { c0[w] = v; c1[w] = mf; }
    }
    __syncthreads();
    if (tid == 0) {
        clip_sims[(bx * 2) * BB + by] =
            (c0[0] + c0[1]) / fmaxf(c1[0] + c1[1], EPSF);
        clip_sims[(bx * 2 + 1) * BB + by] =
            (c0[2] + c0[3]) / fmaxf(c1[2] + c1[3], EPSF);
        float s = 0.0f;
        #pragma unroll
        for (int x = 0; x < 8; ++x) s += redw[x];
        atomicAdd(reg_sum, s);
    }
}

// ---------------------------------------------------------------------------
// Kernel 3: final scalar loss. Single block, 256 threads.
// ---------------------------------------------------------------------------
__global__ __launch_bounds__(256) void k_loss(
    const float* __restrict__ clip_sims, const float* __restrict__ reg_sum,
    float* __restrict__ out) {
    __shared__ float sc[BB][BB + 1];
    __shared__ float lrow[BB], lcol[BB];
    int tid = threadIdx.x;
    for (int idx = tid; idx < BB * BB; idx += 256)
        sc[idx / BB][idx % BB] = clip_sims[idx];
    __syncthreads();
    if (tid < BB) {
        int i = tid;
        float m = sc[i][0];
        #pragma unroll
        for (int j = 1; j < BB; ++j) m = fmaxf(m, sc[i][j]);
        float s = 0.0f;
        #pragma unroll
        for (int j = 0; j < BB; ++j) s += expf(sc[i][j] - m);
        lrow[i] = m + logf(s) - sc[i][i];
    } else if (tid < 2 * BB) {
        int i = tid - BB;
        float m = sc[0][i];
        #pragma unroll
        for (int j = 1; j < BB; ++j) m = fmaxf(m, sc[j][i]);
        float s = 0.0f;
        #pragma unroll
        for (int j = 0; j < BB; ++j) s += expf(sc[j][i] - m);
        lcol[i] = m + logf(s) - sc[i][i];
    }
    __syncthreads();
    if (tid == 0) {
        float tot = 0.0f;
        for (int i = 0; i < BB; ++i) tot += lrow[i] + lcol[i];
        float contrastive = tot / (2.0f * BB);
        double denom = (double)BB * BB * NT * NV;  // 134217728
        float reg = 0.15f * (float)((double)reg_sum[0] / denom);
        out[0] = contrastive + reg;
    }
}

// ---------------------------------------------------------------------------
extern "C" void kernel_launch(void* const* d_in, const int* in_sizes, int n_in,
                              void* d_out, int out_size, void* d_ws, size_t ws_size,
                              hipStream_t stream) {
    const float* tf = (const float*)d_in[0];   // (B, NT, D) fp32
    const float* vf = (const float*)d_in[1];   // (B, NV, D) fp32
    const int* mask = (const int*)d_in[2];     // (B, NT) int32
    float* out = (float*)d_out;                // scalar fp32

    char* ws = (char*)d_ws;
    size_t tn_bytes = (size_t)BB * NT * DD;              // 4 MB fp8
    size_t vn_bytes = (size_t)BB * NV * DD;              // 8 MB fp8
    size_t cs_bytes = (size_t)BB * BB * sizeof(float);   // 16 KB

    uchar* tn = (uchar*)ws;
    uchar* vn = (uchar*)(ws + tn_bytes);
    float* clip_sims = (float*)(ws + tn_bytes + vn_bytes);
    float* reg_sum = (float*)(ws + tn_bytes + vn_bytes + cs_bytes);

    k_normalize<<<(BB * NT + BB * NV) / 4, 256, 0, stream>>>(tf, vf, tn, vn, reg_sum);
    // 2048 blocks: (8192/256) M-tiles x (16384/256) N-tiles = 32 x 64.
    k_gemm<<<32 * 64, 512, 0, stream>>>(tn, vn, mask, clip_sims, reg_sum);
    k_loss<<<1, 256, 0, stream>>>(clip_sims, reg_sum, out);
}

// Round 3
// 419.314 us; speedup vs baseline: 1.0003x; 1.0003x over previous
//
#include <hip/hip_runtime.h>
#include <hip/hip_bf16.h>

// Problem constants
#define BB 64     // batch
#define NT 128    // text tokens
#define NV 256    // visual tokens
#define DD 512    // feature dim (bytes per row in fp8)
#define BKB 128   // K-chunk in bytes: one 16x16x128 f8f6f4 k-step
#define BM 256    // M-tile rows (= 2 text batches)
#define BN 256    // N-tile rows (= 1 visual batch)
#define EPSF 1e-7f

typedef __attribute__((ext_vector_type(8))) int i32x8;
typedef __attribute__((ext_vector_type(4))) int i32x4;
typedef __attribute__((ext_vector_type(4))) float f32x4;

__device__ __forceinline__ void glds16(const uchar* g, uchar* l) {
    __builtin_amdgcn_global_load_lds(
        (const __attribute__((address_space(1))) unsigned int*)g,
        (__attribute__((address_space(3))) unsigned int*)l, 16, 0, 0);
}

// ---------------------------------------------------------------------------
// Kernel 1: L2-normalize rows, write fp8 e4m3 (OCP). Wave per row.
// ---------------------------------------------------------------------------
__global__ __launch_bounds__(256) void k_normalize(
    const float* __restrict__ tf, const float* __restrict__ vf,
    uchar* __restrict__ tn, uchar* __restrict__ vn,
    float* __restrict__ reg_sum) {
    if (blockIdx.x == 0 && threadIdx.x == 0) *reg_sum = 0.0f;
    const int w = threadIdx.x >> 6, l = threadIdx.x & 63;
    const int row = blockIdx.x * 4 + w;
    const float* src;
    uchar* dst;
    if (row < BB * NT) {
        src = tf + (size_t)row * DD;
        dst = tn + (size_t)row * DD;
    } else {
        int r = row - BB * NT;
        src = vf + (size_t)r * DD;
        dst = vn + (size_t)r * DD;
    }
    float4 x0 = ((const float4*)src)[l * 2];
    float4 x1 = ((const float4*)src)[l * 2 + 1];
    float ss = x0.x * x0.x + x0.y * x0.y + x0.z * x0.z + x0.w * x0.w
             + x1.x * x1.x + x1.y * x1.y + x1.z * x1.z + x1.w * x1.w;
    #pragma unroll
    for (int off = 32; off; off >>= 1) ss += __shfl_xor(ss, off, 64);
    float scale = 1.0f / fmaxf(sqrtf(ss), 1e-12f);
    int p0 = __builtin_amdgcn_cvt_pk_fp8_f32(x0.x * scale, x0.y * scale, 0, 0);
    p0 = __builtin_amdgcn_cvt_pk_fp8_f32(x0.z * scale, x0.w * scale, p0, 1);
    int p1 = __builtin_amdgcn_cvt_pk_fp8_f32(x1.x * scale, x1.y * scale, 0, 0);
    p1 = __builtin_amdgcn_cvt_pk_fp8_f32(x1.z * scale, x1.w * scale, p1, 1);
    ((uint2*)dst)[l] = make_uint2((unsigned)p0, (unsigned)p1);
}

// ---------------------------------------------------------------------------
// Kernel 2: 256x256-tile MX-fp8 GEMM, double-buffered LDS, prefetch-then-
// compute with ONE plain __syncthreads() per K-step (verified correct,
// absmax 0.0 in round 2). No inline asm.
//
// ROUND-3 CHANGE (locality fix, single variable): round-2's swizzle gave the
// 32 concurrent blocks on an XCD DISTINCT bx (disjoint 4 MB T working set ->
// L2 thrash, FETCH_SIZE 581 MB, fabric-BW-bound at 345us). New mapping:
// within an XCD, by varies FAST over a private range of 8 (1 MB V, resident
// the whole kernel) and bx varies SLOW (concurrent window = ~4 T-tiles,
// 512 KB). Concurrent working set 1.5 MB << 4 MB L2; projected L2-miss
// traffic ~40 MB total.
// ---------------------------------------------------------------------------
__global__ __launch_bounds__(512, 2) void k_gemm(
    const uchar* __restrict__ tn, const uchar* __restrict__ vn,
    const int* __restrict__ mask,
    float* __restrict__ clip_sims, float* __restrict__ reg_sum) {
    __shared__ uchar sT[2][BM * BKB];   // 2 x 32 KB
    __shared__ uchar sV[2][BN * BKB];   // 2 x 32 KB
    __shared__ float maxbuf[BM][4];     // row-max partials per wave col-group
    __shared__ float redw[8];
    __shared__ float c0[4], c1[4];

    // XCD-aware mapping (bijective over 2048 blocks):
    //   x  = bid & 7   : XCD (hardware round-robin heuristic)
    //   k  = bid >> 3  : sequence index within XCD (0..255)
    //   by = x*8 + (k & 7)  : fast, 8 visual batches private to this XCD
    //   bx = k >> 3         : slow, sweeps all 32 text-pair tiles
    const int bid = blockIdx.x;
    const int x = bid & 7;
    const int k = bid >> 3;
    const int bx = k >> 3;           // text-pair tile (0..31)
    const int by = x * 8 + (k & 7);  // visual batch j (0..63)

    const int tid = threadIdx.x;
    const int l = tid & 63, w = tid >> 6;
    const int wr = w >> 2, wc = w & 3;      // wave row-group (0..1), col-group (0..3)
    const int m15 = l & 15, q = l >> 4;

    const uchar* tbase = tn + (size_t)bx * BM * DD;
    const uchar* vbase = vn + (size_t)by * NV * DD;

    // Staging: 16B unit f -> row r = f>>3, phys granule p = f&7 holds
    // logical granule g = (p - r) & 7. Same geometry for T and V (256x128B).
    int soff[4];
    #pragma unroll
    for (int s = 0; s < 4; ++s) {
        int f = s * 512 + tid;
        int r = f >> 3, p = f & 7, g = (p - r) & 7;
        soff[s] = r * DD + g * 16;
    }

    // Fragment read addresses: lane holds k = q*32..q*32+31 of its row,
    // logical granules 2q, 2q+1 -> phys (2q+row)&7, (2q+1+row)&7.
    int a_b0[8], a_b1[8], b_b0[4], b_b1[4];
    #pragma unroll
    for (int rt = 0; rt < 8; ++rt) {
        int row = wr * 128 + rt * 16 + m15;
        a_b0[rt] = row * BKB + (((2 * q + row) & 7) * 16);
        a_b1[rt] = row * BKB + (((2 * q + 1 + row) & 7) * 16);
    }
    #pragma unroll
    for (int ct = 0; ct < 4; ++ct) {
        int row = wc * 64 + ct * 16 + m15;
        b_b0[ct] = row * BKB + (((2 * q + row) & 7) * 16);
        b_b1[ct] = row * BKB + (((2 * q + 1 + row) & 7) * 16);
    }

    f32x4 acc[8][4];
    #pragma unroll
    for (int rt = 0; rt < 8; ++rt)
        #pragma unroll
        for (int ct = 0; ct < 4; ++ct) acc[rt][ct] = (f32x4){0.f, 0.f, 0.f, 0.f};

    // Prologue: stage chunk 0 into buffer 0, then one full sync.
    #pragma unroll
    for (int s = 0; s < 4; ++s) {
        glds16(tbase + soff[s], sT[0] + (s * 512 + tid) * 16);
        glds16(vbase + soff[s], sV[0] + (s * 512 + tid) * 16);
    }
    __syncthreads();

    #pragma unroll
    for (int ks = 0; ks < 4; ++ks) {
        const int cur = ks & 1, nxt = cur ^ 1;
        // Issue next chunk's staging FIRST (overlaps with compute below).
        // Overwrite of buf[nxt] is safe: the barrier at the end of the
        // previous iteration guarantees all waves finished reading it.
        if (ks < 3) {
            const int kk = (ks + 1) * BKB;
            #pragma unroll
            for (int s = 0; s < 4; ++s) {
                glds16(tbase + soff[s] + kk, sT[nxt] + (s * 512 + tid) * 16);
                glds16(vbase + soff[s] + kk, sV[nxt] + (s * 512 + tid) * 16);
            }
        }

        // Compute current chunk.
        i32x8 b[4];
        #pragma unroll
        for (int ct = 0; ct < 4; ++ct) {
            i32x4 lo = *(const i32x4*)(sV[cur] + b_b0[ct]);
            i32x4 hi = *(const i32x4*)(sV[cur] + b_b1[ct]);
            b[ct] = (i32x8){lo.x, lo.y, lo.z, lo.w, hi.x, hi.y, hi.z, hi.w};
        }
        #pragma unroll
        for (int rt = 0; rt < 8; ++rt) {
            i32x4 lo = *(const i32x4*)(sT[cur] + a_b0[rt]);
            i32x4 hi = *(const i32x4*)(sT[cur] + a_b1[rt]);
            i32x8 a = (i32x8){lo.x, lo.y, lo.z, lo.w, hi.x, hi.y, hi.z, hi.w};
            #pragma unroll
            for (int ct = 0; ct < 4; ++ct)
                acc[rt][ct] = __builtin_amdgcn_mfma_scale_f32_16x16x128_f8f6f4(
                    a, b[ct], acc[rt][ct],
                    0 /*A fmt=fp8*/, 0 /*B fmt=fp8*/,
                    0, 127 /*scaleA=1.0*/, 0, 127 /*scaleB=1.0*/);
        }

        // One barrier per K-step: drains the prefetch (already landed under
        // the MFMAs) and fences the buffer swap.
        __syncthreads();
    }

    // Epilogue 1: reg partial = sum of min(s,0)^2 over this lane's 128 values.
    float rp = 0.0f;
    #pragma unroll
    for (int rt = 0; rt < 8; ++rt)
        #pragma unroll
        for (int ct = 0; ct < 4; ++ct)
            #pragma unroll
            for (int r = 0; r < 4; ++r) {
                float m = fminf(acc[rt][ct][r], 0.0f);
                rp = fmaf(m, m, rp);
            }

    // Epilogue 2: row max. C/D layout: col = lane&15, row = q*4 + reg.
    #pragma unroll
    for (int rt = 0; rt < 8; ++rt)
        #pragma unroll
        for (int r = 0; r < 4; ++r) {
            float m = acc[rt][0][r];
            #pragma unroll
            for (int ct = 1; ct < 4; ++ct) m = fmaxf(m, acc[rt][ct][r]);
            #pragma unroll
            for (int msk = 1; msk < 16; msk <<= 1)
                m = fmaxf(m, __shfl_xor(m, msk, 64));
            if (m15 == 0)
                maxbuf[wr * 128 + rt * 16 + q * 4 + r][wc] = m;
        }

    #pragma unroll
    for (int off = 32; off; off >>= 1) rp += __shfl_down(rp, off, 64);
    if (l == 0) redw[w] = rp;
    __syncthreads();

    // Fused clip: masked mean of row maxes per 128-token group.
    // Waves 0-1 -> batch 2bx (rows 0..127), waves 2-3 -> batch 2bx+1.
    if (tid < 256) {
        float rm = fmaxf(fmaxf(maxbuf[tid][0], maxbuf[tid][1]),
                         fmaxf(maxbuf[tid][2], maxbuf[tid][3]));
        int ib = bx * 2 + (tid >> 7);
        float mf = (float)mask[ib * NT + (tid & 127)];
        float v = rm * mf;
        #pragma unroll
        for (int off = 32; off; off >>= 1) {
            v += __shfl_down(v, off, 64);
            mf += __shfl_down(mf, off, 64);
        }
        if (l == 0) { c0[w] = v; c1[w] = mf; }
    }
    __syncthreads();
    if (tid == 0) {
        clip_sims[(bx * 2) * BB + by] =
            (c0[0] + c0[1]) / fmaxf(c1[0] + c1[1], EPSF);
        clip_sims[(bx * 2 + 1) * BB + by] =
            (c0[2] + c0[3]) / fmaxf(c1[2] + c1[3], EPSF);
        float s = 0.0f;
        #pragma unroll
        for (int x2 = 0; x2 < 8; ++x2) s += redw[x2];
        atomicAdd(reg_sum, s);
    }
}

// ---------------------------------------------------------------------------
// Kernel 3: final scalar loss. Single block, 256 threads.
// ---------------------------------------------------------------------------
__global__ __launch_bounds__(256) void k_loss(
    const float* __restrict__ clip_sims, const float* __restrict__ reg_sum,
    float* __restrict__ out) {
    __shared__ float sc[BB][BB + 1];
    __shared__ float lrow[BB], lcol[BB];
    int tid = threadIdx.x;
    for (int idx = tid; idx < BB * BB; idx += 256)
        sc[idx / BB][idx % BB] = clip_sims[idx];
    __syncthreads();
    if (tid < BB) {
        int i = tid;
        float m = sc[i][0];
        #pragma unroll
        for (int j = 1; j < BB; ++j) m = fmaxf(m, sc[i][j]);
        float s = 0.0f;
        #pragma unroll
        for (int j = 0; j < BB; ++j) s += expf(sc[i][j] - m);
        lrow[i] = m + logf(s) - sc[i][i];
    } else if (tid < 2 * BB) {
        int i = tid - BB;
        float m = sc[0][i];
        #pragma unroll
        for (int j = 1; j < BB; ++j) m = fmaxf(m, sc[j][i]);
        float s = 0.0f;
        #pragma unroll
        for (int j = 0; j < BB; ++j) s += expf(sc[j][i] - m);
        lcol[i] = m + logf(s) - sc[i][i];
    }
    __syncthreads();
    if (tid == 0) {
        float tot = 0.0f;
        for (int i = 0; i < BB; ++i) tot += lrow[i] + lcol[i];
        float contrastive = tot / (2.0f * BB);
        double denom = (double)BB * BB * NT * NV;  // 134217728
        float reg = 0.15f * (float)((double)reg_sum[0] / denom);
        out[0] = contrastive + reg;
    }
}

// ---------------------------------------------------------------------------
extern "C" void kernel_launch(void* const* d_in, const int* in_sizes, int n_in,
                              void* d_out, int out_size, void* d_ws, size_t ws_size,
                              hipStream_t stream) {
    const float* tf = (const float*)d_in[0];   // (B, NT, D) fp32
    const float* vf = (const float*)d_in[1];   // (B, NV, D) fp32
    const int* mask = (const int*)d_in[2];     // (B, NT) int32
    float* out = (float*)d_out;                // scalar fp32

    char* ws = (char*)d_ws;
    size_t tn_bytes = (size_t)BB * NT * DD;              // 4 MB fp8
    size_t vn_bytes = (size_t)BB * NV * DD;              // 8 MB fp8
    size_t cs_bytes = (size_t)BB * BB * sizeof(float);   // 16 KB

    uchar* tn = (uchar*)ws;
    uchar* vn = (uchar*)(ws + tn_bytes);
    float* clip_sims = (float*)(ws + tn_bytes + vn_bytes);
    float* reg_sum = (float*)(ws + tn_bytes + vn_bytes + cs_bytes);

    k_normalize<<<(BB * NT + BB * NV) / 4, 256, 0, stream>>>(tf, vf, tn, vn, reg_sum);
    // 2048 blocks: (8192/256) M-tiles x (16384/256) N-tiles = 32 x 64.
    k_gemm<<<32 * 64, 512, 0, stream>>>(tn, vn, mask, clip_sims, reg_sum);
    k_loss<<<1, 256, 0, stream>>>(clip_sims, reg_sum, out);
}

// Round 4
// 233.093 us; speedup vs baseline: 1.7995x; 1.7989x over previous
//
#include <hip/hip_runtime.h>
#include <hip/hip_bf16.h>

// Problem constants
#define BB 64     // batch
#define NT 128    // text tokens
#define NV 256    // visual tokens
#define DD 512    // feature dim (bytes per row in fp8)
#define BKB 128   // K-chunk in bytes: one 16x16x128 f8f6f4 k-step
#define EPSF 1e-7f

typedef __attribute__((ext_vector_type(8))) int i32x8;
typedef __attribute__((ext_vector_type(4))) int i32x4;
typedef __attribute__((ext_vector_type(4))) float f32x4;

__device__ __forceinline__ void glds16(const uchar* g, uchar* l) {
    __builtin_amdgcn_global_load_lds(
        (const __attribute__((address_space(1))) unsigned int*)g,
        (__attribute__((address_space(3))) unsigned int*)l, 16, 0, 0);
}

// ---------------------------------------------------------------------------
// Kernel 1: L2-normalize rows, write fp8 e4m3 (OCP). Wave per row.
// ---------------------------------------------------------------------------
__global__ __launch_bounds__(256) void k_normalize(
    const float* __restrict__ tf, const float* __restrict__ vf,
    uchar* __restrict__ tn, uchar* __restrict__ vn,
    float* __restrict__ reg_sum) {
    if (blockIdx.x == 0 && threadIdx.x == 0) *reg_sum = 0.0f;
    const int w = threadIdx.x >> 6, l = threadIdx.x & 63;
    const int row = blockIdx.x * 4 + w;
    const float* src;
    uchar* dst;
    if (row < BB * NT) {
        src = tf + (size_t)row * DD;
        dst = tn + (size_t)row * DD;
    } else {
        int r = row - BB * NT;
        src = vf + (size_t)r * DD;
        dst = vn + (size_t)r * DD;
    }
    float4 x0 = ((const float4*)src)[l * 2];
    float4 x1 = ((const float4*)src)[l * 2 + 1];
    float ss = x0.x * x0.x + x0.y * x0.y + x0.z * x0.z + x0.w * x0.w
             + x1.x * x1.x + x1.y * x1.y + x1.z * x1.z + x1.w * x1.w;
    #pragma unroll
    for (int off = 32; off; off >>= 1) ss += __shfl_xor(ss, off, 64);
    float scale = 1.0f / fmaxf(sqrtf(ss), 1e-12f);
    int p0 = __builtin_amdgcn_cvt_pk_fp8_f32(x0.x * scale, x0.y * scale, 0, 0);
    p0 = __builtin_amdgcn_cvt_pk_fp8_f32(x0.z * scale, x0.w * scale, p0, 1);
    int p1 = __builtin_amdgcn_cvt_pk_fp8_f32(x1.x * scale, x1.y * scale, 0, 0);
    p1 = __builtin_amdgcn_cvt_pk_fp8_f32(x1.z * scale, x1.w * scale, p1, 1);
    ((uint2*)dst)[l] = make_uint2((unsigned)p0, (unsigned)p1);
}

// ---------------------------------------------------------------------------
// Kernel 2: exact round-0 geometry (128x256 tile, block per (i,j) pair,
// acc[4][4] = 64 regs/thread -- the register shape MEASURED spill-free at
// VGPR=128, WRITE_SIZE=30MB) + double-buffered pipelining.
//
// ROUND-4 DIAGNOSIS: rounds 2-3's 256x256 tile (acc[8][4]=128 regs + hoisted
// frags) spilled the accumulator to scratch: WRITE_SIZE 626 MB ~= 600 B/thr
// = the acc array round-tripping through HBM. That -- not L2 locality -- was
// the whole regression. This round keeps ONLY the pipelining idea:
//   * 4 DISTINCT __shared__ buffers (sT0/sT1/sV0/sV1) so alias analysis can
//     distinguish prefetch writes from current-buffer ds_reads (no forced
//     conservative vmcnt drain before fragment reads).
//   * fully unrolled schedule: stage(next) issued BEFORE compute(cur), one
//     __syncthreads() per K-step (schedule correctness-verified in r2/r3,
//     absmax 0.0). The barrier's implicit vmcnt(0) lands after ~1100 cy of
//     MFMA, so the prefetch is already home.
// LDS 96 KB + 2 KB epilogue -> 1 block/CU; __launch_bounds__(512,2) keeps
// the 256-VGPR/wave budget (~100 regs of slack -> no spill pressure).
// ---------------------------------------------------------------------------
__global__ __launch_bounds__(512, 2) void k_gemm(
    const uchar* __restrict__ tn, const uchar* __restrict__ vn,
    const int* __restrict__ mask,
    float* __restrict__ clip_sims, float* __restrict__ reg_sum) {
    __shared__ uchar sT0[NT * BKB];   // 16 KB
    __shared__ uchar sT1[NT * BKB];   // 16 KB
    __shared__ uchar sV0[NV * BKB];   // 32 KB
    __shared__ uchar sV1[NV * BKB];   // 32 KB
    __shared__ float maxbuf[NT][4];   // row-max partials per wave col-group
    __shared__ float redw[8];
    __shared__ float c0[2], c1[2];

    const int i = blockIdx.x, j = blockIdx.y;
    const int tid = threadIdx.x;
    const int l = tid & 63, w = tid >> 6;
    const int wr = w >> 2, wc = w & 3;      // wave row-group (0..1), col-group (0..3)
    const int m15 = l & 15, q = l >> 4;

    const uchar* tbase = tn + (size_t)i * NT * DD;
    const uchar* vbase = vn + (size_t)j * NV * DD;

    // Staging: 16B unit f -> row r = f>>3, phys granule p = f&7 holds
    // logical granule g = (p - r) & 7.  src = r*DD + kk + g*16.
    int t_off[2], v_off[4];
    #pragma unroll
    for (int s = 0; s < 2; ++s) {
        int f = s * 512 + tid;
        int r = f >> 3, p = f & 7, g = (p - r) & 7;
        t_off[s] = r * DD + g * 16;
    }
    #pragma unroll
    for (int s = 0; s < 4; ++s) {
        int f = s * 512 + tid;
        int r = f >> 3, p = f & 7, g = (p - r) & 7;
        v_off[s] = r * DD + g * 16;
    }

    // Fragment read addresses: lane holds k = q*32..q*32+31 of its row,
    // logical granules 2q, 2q+1 -> phys (2q+row)&7, (2q+1+row)&7.
    int a_b0[4], a_b1[4], b_b0[4], b_b1[4];
    #pragma unroll
    for (int rt = 0; rt < 4; ++rt) {
        int row = wr * 64 + rt * 16 + m15;
        a_b0[rt] = row * BKB + (((2 * q + row) & 7) * 16);
        a_b1[rt] = row * BKB + (((2 * q + 1 + row) & 7) * 16);
    }
    #pragma unroll
    for (int ct = 0; ct < 4; ++ct) {
        int row = wc * 64 + ct * 16 + m15;
        b_b0[ct] = row * BKB + (((2 * q + row) & 7) * 16);
        b_b1[ct] = row * BKB + (((2 * q + 1 + row) & 7) * 16);
    }

    f32x4 acc[4][4];
    #pragma unroll
    for (int rt = 0; rt < 4; ++rt)
        #pragma unroll
        for (int ct = 0; ct < 4; ++ct) acc[rt][ct] = (f32x4){0.f, 0.f, 0.f, 0.f};

    auto stage = [&](uchar* dT, uchar* dV, int kk) {
        #pragma unroll
        for (int s = 0; s < 2; ++s)
            glds16(tbase + t_off[s] + kk, dT + (s * 512 + tid) * 16);
        #pragma unroll
        for (int s = 0; s < 4; ++s)
            glds16(vbase + v_off[s] + kk, dV + (s * 512 + tid) * 16);
    };
    auto compute = [&](const uchar* bT, const uchar* bV) {
        i32x8 bf[4];
        #pragma unroll
        for (int ct = 0; ct < 4; ++ct) {
            i32x4 lo = *(const i32x4*)(bV + b_b0[ct]);
            i32x4 hi = *(const i32x4*)(bV + b_b1[ct]);
            bf[ct] = (i32x8){lo.x, lo.y, lo.z, lo.w, hi.x, hi.y, hi.z, hi.w};
        }
        #pragma unroll
        for (int rt = 0; rt < 4; ++rt) {
            i32x4 lo = *(const i32x4*)(bT + a_b0[rt]);
            i32x4 hi = *(const i32x4*)(bT + a_b1[rt]);
            i32x8 a = (i32x8){lo.x, lo.y, lo.z, lo.w, hi.x, hi.y, hi.z, hi.w};
            #pragma unroll
            for (int ct = 0; ct < 4; ++ct)
                acc[rt][ct] = __builtin_amdgcn_mfma_scale_f32_16x16x128_f8f6f4(
                    a, bf[ct], acc[rt][ct],
                    0 /*A fmt=fp8*/, 0 /*B fmt=fp8*/,
                    0, 127 /*scaleA=1.0*/, 0, 127 /*scaleB=1.0*/);
        }
    };

    // Pipelined schedule: stage(next) issued before compute(cur); one
    // barrier per K-step fences both the prefetch drain and the buffer swap.
    stage(sT0, sV0, 0);
    __syncthreads();

    stage(sT1, sV1, 1 * BKB);
    compute(sT0, sV0);
    __syncthreads();

    stage(sT0, sV0, 2 * BKB);
    compute(sT1, sV1);
    __syncthreads();

    stage(sT1, sV1, 3 * BKB);
    compute(sT0, sV0);
    __syncthreads();

    compute(sT1, sV1);

    // Epilogue 1: reg partial = sum of min(s,0)^2 over this lane's 64 values.
    float rp = 0.0f;
    #pragma unroll
    for (int rt = 0; rt < 4; ++rt)
        #pragma unroll
        for (int ct = 0; ct < 4; ++ct)
            #pragma unroll
            for (int r = 0; r < 4; ++r) {
                float m = fminf(acc[rt][ct][r], 0.0f);
                rp = fmaf(m, m, rp);
            }

    // Epilogue 2: row max. C/D layout: col = lane&15, row = q*4 + reg.
    #pragma unroll
    for (int rt = 0; rt < 4; ++rt)
        #pragma unroll
        for (int r = 0; r < 4; ++r) {
            float m = acc[rt][0][r];
            #pragma unroll
            for (int ct = 1; ct < 4; ++ct) m = fmaxf(m, acc[rt][ct][r]);
            #pragma unroll
            for (int msk = 1; msk < 16; msk <<= 1)
                m = fmaxf(m, __shfl_xor(m, msk, 64));
            if (m15 == 0)
                maxbuf[wr * 64 + rt * 16 + q * 4 + r][wc] = m;
        }

    #pragma unroll
    for (int off = 32; off; off >>= 1) rp += __shfl_down(rp, off, 64);
    if (l == 0) redw[w] = rp;
    __syncthreads();

    // Fused clip: masked mean of row maxes over the 128 text tokens.
    if (tid < NT) {
        float rm = fmaxf(fmaxf(maxbuf[tid][0], maxbuf[tid][1]),
                         fmaxf(maxbuf[tid][2], maxbuf[tid][3]));
        float mf = (float)mask[i * NT + tid];
        float v = rm * mf;
        #pragma unroll
        for (int off = 32; off; off >>= 1) {
            v += __shfl_down(v, off, 64);
            mf += __shfl_down(mf, off, 64);
        }
        if (l == 0) { c0[w] = v; c1[w] = mf; }
    }
    __syncthreads();
    if (tid == 0) {
        clip_sims[i * BB + j] = (c0[0] + c0[1]) / fmaxf(c1[0] + c1[1], EPSF);
        float s = 0.0f;
        #pragma unroll
        for (int x = 0; x < 8; ++x) s += redw[x];
        atomicAdd(reg_sum, s);
    }
}

// ---------------------------------------------------------------------------
// Kernel 3: final scalar loss. Single block, 256 threads.
// ---------------------------------------------------------------------------
__global__ __launch_bounds__(256) void k_loss(
    const float* __restrict__ clip_sims, const float* __restrict__ reg_sum,
    float* __restrict__ out) {
    __shared__ float sc[BB][BB + 1];
    __shared__ float lrow[BB], lcol[BB];
    int tid = threadIdx.x;
    for (int idx = tid; idx < BB * BB; idx += 256)
        sc[idx / BB][idx % BB] = clip_sims[idx];
    __syncthreads();
    if (tid < BB) {
        int i = tid;
        float m = sc[i][0];
        #pragma unroll
        for (int j = 1; j < BB; ++j) m = fmaxf(m, sc[i][j]);
        float s = 0.0f;
        #pragma unroll
        for (int j = 0; j < BB; ++j) s += expf(sc[i][j] - m);
        lrow[i] = m + logf(s) - sc[i][i];
    } else if (tid < 2 * BB) {
        int i = tid - BB;
        float m = sc[0][i];
        #pragma unroll
        for (int j = 1; j < BB; ++j) m = fmaxf(m, sc[j][i]);
        float s = 0.0f;
        #pragma unroll
        for (int j = 0; j < BB; ++j) s += expf(sc[j][i] - m);
        lcol[i] = m + logf(s) - sc[i][i];
    }
    __syncthreads();
    if (tid == 0) {
        float tot = 0.0f;
        for (int i = 0; i < BB; ++i) tot += lrow[i] + lcol[i];
        float contrastive = tot / (2.0f * BB);
        double denom = (double)BB * BB * NT * NV;  // 134217728
        float reg = 0.15f * (float)((double)reg_sum[0] / denom);
        out[0] = contrastive + reg;
    }
}

// ---------------------------------------------------------------------------
extern "C" void kernel_launch(void* const* d_in, const int* in_sizes, int n_in,
                              void* d_out, int out_size, void* d_ws, size_t ws_size,
                              hipStream_t stream) {
    const float* tf = (const float*)d_in[0];   // (B, NT, D) fp32
    const float* vf = (const float*)d_in[1];   // (B, NV, D) fp32
    const int* mask = (const int*)d_in[2];     // (B, NT) int32
    float* out = (float*)d_out;                // scalar fp32

    char* ws = (char*)d_ws;
    size_t tn_bytes = (size_t)BB * NT * DD;              // 4 MB fp8
    size_t vn_bytes = (size_t)BB * NV * DD;              // 8 MB fp8
    size_t cs_bytes = (size_t)BB * BB * sizeof(float);   // 16 KB

    uchar* tn = (uchar*)ws;
    uchar* vn = (uchar*)(ws + tn_bytes);
    float* clip_sims = (float*)(ws + tn_bytes + vn_bytes);
    float* reg_sum = (float*)(ws + tn_bytes + vn_bytes + cs_bytes);

    k_normalize<<<(BB * NT + BB * NV) / 4, 256, 0, stream>>>(tf, vf, tn, vn, reg_sum);
    k_gemm<<<dim3(BB, BB), 512, 0, stream>>>(tn, vn, mask, clip_sims, reg_sum);
    k_loss<<<1, 256, 0, stream>>>(clip_sims, reg_sum, out);
}